// Round 9
// baseline (165.372 us; speedup 1.0000x reference)
//
#include <hip/hip_runtime.h>
#include <stdint.h>

#define B_ 8
#define T_ 512
#define M_ 16
#define D_ 128
#define P_ 256
#define H_ 8
#define E_ 32

typedef __attribute__((ext_vector_type(8))) short  short8;
typedef __attribute__((ext_vector_type(4))) short  short4v;
typedef __attribute__((ext_vector_type(4))) float  float4v;
typedef __attribute__((ext_vector_type(2))) unsigned int uint2v;
typedef __attribute__((ext_vector_type(4))) unsigned int uint4v;
typedef __attribute__((ext_vector_type(2))) __bf16 bf16x2;

#define MFMA32(a,b,c) __builtin_amdgcn_mfma_f32_16x16x32_bf16(a,b,c,0,0,0)   // K=32, short8 ops
#define EXP2F(x) __builtin_amdgcn_exp2f(x)

#define C2 0.2550332772062413f   // log2(e)/sqrt(E)

// cold-path scalar RNE (prep only)
static __device__ __forceinline__ unsigned short f2bf(float x){
  unsigned int u = __builtin_bit_cast(unsigned int, x);
  u += 0x7FFFu + ((u >> 16) & 1u);           // RNE
  return (unsigned short)(u >> 16);
}

// hot-path: plain __bf16 casts -> compiler emits v_cvt_pk_bf16_f32 (RNE).
static __device__ __forceinline__ unsigned int pk2(float a, float b){
  bf16x2 h; h[0] = (__bf16)a; h[1] = (__bf16)b;
  return __builtin_bit_cast(unsigned int, h);
}

static __device__ __forceinline__ short4v pack4(float4v v){
  uint2v u; u.x = pk2(v[0], v[1]); u.y = pk2(v[2], v[3]);
  return __builtin_bit_cast(short4v, u);
}

static __device__ __forceinline__ short8 pack8(float4v a, float4v b){
  uint4v u; u.x = pk2(a[0],a[1]); u.y = pk2(a[2],a[3]);
  u.z = pk2(b[0],b[1]); u.w = pk2(b[2],b[3]);
  return __builtin_bit_cast(short8, u);
}

static __device__ __forceinline__ short8 cat44(short4v lo, short4v hi){
  short8 r;
  r[0]=lo[0]; r[1]=lo[1]; r[2]=lo[2]; r[3]=lo[3];
  r[4]=hi[0]; r[5]=hi[1]; r[6]=hi[2]; r[7]=hi[3];
  return r;
}

// ------- kernel 0: WT[z][p][d] bf16 (Wq pre-scaled by C2) --------------------
// Coalesced: p fastest -> contiguous reads. Q/K rows permuted so projection
// passes directly produce the e-chunk-of-8 layout for K=32 MFMA operands:
//   storage row w = eh*16 + q4*4 + r  holds true column  e = q4*8 + eh*4 + r.
__global__ void prep(const float* __restrict__ Wq, const float* __restrict__ Wk,
                     const float* __restrict__ Wv, uint16_t* __restrict__ WT){
  int idx = blockIdx.x*256 + threadIdx.x;      // 384*256 = 98304 = 3*P*D
  int p = idx & (P_-1);
  int d = (idx >> 8) & (D_-1);
  int z = idx >> 15;
  int col = p;
  if (z < 2){                                  // Q, K: permute within-head rows
    int w = p & 31;
    int e = ((w>>2)&3)*8 + ((w>>4)&1)*4 + (w&3);
    col = (p & ~31) | e;
  }
  const float* W = (z==0) ? Wq : (z==1) ? Wk : Wv;
  float sc = (z==0) ? C2 : 1.0f;
  WT[(z<<15) + (p<<7) + d] = f2bf(W[d*P_ + col] * sc);
}

// ---------------- fused QKV + masked attention, one block per (b,m,h) ------
// r9: r8's compaction shifted the bottleneck to the projection phase, and
// its +~5 live regs caused minor spills (WRITE 65.6->75.8MB). Fixes:
//  (1) K+V projections MERGED: shared af reads, 2 weight loads + 8 MFMAs
//      per (eh,kc) step -> 2x MFMA ILP, half the load-stall exposure in
//      the longest serial phase. Live set af(64)+accs(32)+wgts(8) ~ 112.
//  (2) tg[4] array dropped -- compaction target recomputed via inline
//      __shfl at the single merged scatter site (-4 persistent VGPRs).
// r8 recap: mask is block-shared over s, ~50% dense; K/V compacted to
// valid s (ballot+prefix), s-loop runs nsb=ceil(nv/32)~8.5 blocks of 32.
__global__ __launch_bounds__(512, 4) void attn_fused(
    const float* __restrict__ inp, const uint16_t* __restrict__ WT,
    const float* __restrict__ bq, const float* __restrict__ bk,
    const float* __restrict__ bv, const int* __restrict__ mask,
    float* __restrict__ out){
  // bytes [0,65536): staging scratch (512 rows x 128B bf16), later
  //   Kb = [0,32768) K[sc][e] slot-swizzled, Vt = [32768,65536) V^T[e][sc]
  // bytes [65536,67584): Madd (512 f32: 0 for sc<nv, -1e30 pad)
  // bytes [67584,67616): wcnt (8 ints, per-wave valid counts)
  __shared__ __align__(16) uint16_t smem[(65536 + 2048 + 64)/2];
  uint16_t* Kb   = smem;              // uint16 units: rows of 32 (64B)
  uint16_t* Vt   = smem + 16384;
  float*    Madd = (float*)(smem + 32768);
  int*      wcnt = (int*)(smem + 32768 + 1024);

  const int bx = blockIdx.x;                // 1024
  const int h = bx >> 7, bm = bx & 127;     // same-bm blocks -> same XCD (bx%8 = bm%8)
  const int b = bm >> 4, m = bm & 15;
  const int tid = threadIdx.x;
  const int wave = tid >> 6, lane = tid & 63;
  const int q4 = lane >> 4, c = lane & 15;
  const int t0 = wave*64;

  // own-mask load (s = tid); latency hidden under staging
  const int mv = mask[((size_t)(b*T_ + tid))*M_ + m];

  // ---- stage inp -> LDS (bf16, swizzled) -> read MFMA fragments ----
  // scratch row t: 128B = current 64-d half, 16B slots, slot ^= (t&7)
  short8 af[4][4];   // [tj][kc]
  {
    const float* src0 = inp + (size_t)((b*T_ + t0)*M_ + m)*D_ + c*4;
    for (int hh=0; hh<2; hh++){              // d halves: [0,64), [64,128)
      for (int jb=0; jb<2; jb++){            // 2 batches of 8 loads (reg cap)
        float4v stg[8];
        for (int j=0; j<8; j++){
          int r = jb*32 + j*4 + q4;          // row within wave's 64
          stg[j] = *(const float4v*)(src0 + (size_t)r*(M_*D_) + hh*64);
        }
        for (int j=0; j<8; j++){
          int r = t0 + jb*32 + j*4 + q4;
          short4v s4 = pack4(stg[j]);
          *(short4v*)(smem + r*64 + ((((c>>1) ^ (r&7))<<3) + ((c&1)<<2))) = s4;
        }
      }
      // fragments of this half: kc = hh*2+kh, d = kc*32 + q4*8 .. +7
      for (int tj=0; tj<4; tj++){
        int r2 = t0 + tj*16 + c;
        af[tj][hh*2+0] = *(const short8*)(smem + r2*64 + (((q4    ) ^ (r2&7))<<3));
        af[tj][hh*2+1] = *(const short8*)(smem + r2*64 + (((q4 | 4) ^ (r2&7))<<3));
      }
      // half1 staging overwrites same rows: same-wave DS ops execute in order
    }
  }

  // ---- wave valid-counts (before the barrier) ----
  const unsigned long long bal = __ballot(mv != 0);
  const int lanepfx = __popcll(bal & ((1ull << lane) - 1ull));
  if (lane == 0) wcnt[wave] = __popcll(bal);

  __syncthreads();   // staging scratch free; wcnt visible

  // ---- block prefix: compacted target for s = tid ----
  int off = 0, nv = 0;
  for (int w = 0; w < 8; w++){
    int cw = wcnt[w];
    nv += cw;
    if (w < wave) off += cw;
  }
  nv = __builtin_amdgcn_readfirstlane(nv);
  const int nsb = (nv + 31) >> 5;
  const int myt = (mv != 0) ? (off + lanepfx) : -1;

  // Madd + zero the pad rows of Kb/Vt (disjoint from valid scatter targets)
  Madd[tid] = (tid < nv) ? 0.0f : -1e30f;
  for (int j = nv + tid; j < nsb*32; j += 512){
    short8 z8 = {0,0,0,0,0,0,0,0};
    short8* kp = (short8*)(Kb + j*32);
    kp[0]=z8; kp[1]=z8; kp[2]=z8; kp[3]=z8;
    for (int e = 0; e < E_; e++)
      Vt[e*T_ + ((((j>>2) + 2*e) & 127)*4) + (j&3)] = 0;
  }

  const uint16_t* WQ = WT                       + (size_t)(h*E_)*D_;
  const uint16_t* WK = WT + (size_t)1*P_*D_     + (size_t)(h*E_)*D_;
  const uint16_t* WV = WT + (size_t)2*P_*D_     + (size_t)(h*E_)*D_;
  float4v zf = {0.f,0.f,0.f,0.f};

  // ---- K+V projections MERGED -> Kb[tgt][e] and Vt[e][tgt] ----
  // K pass eh yields e = q4*8+eh*4+r (permuted weights); V identity rows.
  // Kb byte addr = tgt*64 + slot*16 + eh*8, slot = q4 ^ (tgt&3)
  // Vt slot stagger 2e (conflict-free s-loop reads)
  for (int eh=0; eh<2; eh++){
    float4v ka[4], va[4];
    for (int j=0;j<4;j++){ ka[j]=zf; va[j]=zf; }
    for (int kc=0; kc<4; kc++){
      short8 wk = *(const short8*)(WK + (size_t)(eh*16 + c)*D_ + kc*32 + q4*8);
      short8 wv = *(const short8*)(WV + (size_t)(eh*16 + c)*D_ + kc*32 + q4*8);
      for (int sj=0; sj<4; sj++){
        ka[sj] = MFMA32(wk, af[sj][kc], ka[sj]);
        va[sj] = MFMA32(wv, af[sj][kc], va[sj]);
      }
    }
    float4v bk4 = *(const float4v*)(bk + h*E_ + q4*8 + eh*4);
    float4v bv4 = *(const float4v*)(bv + h*E_ + eh*16 + q4*4);
    for (int sj=0; sj<4; sj++){
      int t = __shfl(myt, sj*16 + c);      // compaction target of s=t0+sj*16+c
      short4v kv = pack4(ka[sj] + bk4);
      short4v vv = pack4(va[sj] + bv4);
      if (t >= 0){
        *(short4v*)(Kb + t*32 + ((q4 ^ (t&3))<<3) + eh*4) = kv;
        for (int r=0; r<4; r++){
          int e = eh*16 + q4*4 + r;
          Vt[e*T_ + ((((t>>2) + 2*e) & 127)*4) + (t&3)] = (uint16_t)vv[r];
        }
      }
    }
  }
  // ---- Q projection -> q8 regs: concat(pass0,pass1) = e chunk q4*8..q4*8+7 ----
  short8 q8[4];
  {
    short4v qtmp[4][2];
    for (int eh=0; eh<2; eh++){
      float4v qa[4]; for (int j=0;j<4;j++) qa[j]=zf;
      for (int kc=0; kc<4; kc++){
        short8 w = *(const short8*)(WQ + (size_t)(eh*16 + c)*D_ + kc*32 + q4*8);
        for (int tj=0; tj<4; tj++) qa[tj] = MFMA32(w, af[tj][kc], qa[tj]);
      }
      float4v bq4 = *(const float4v*)(bq + h*E_ + q4*8 + eh*4);
      bq4 *= C2;
      for (int tj=0; tj<4; tj++) qtmp[tj][eh] = pack4(qa[tj] + bq4);
    }
    for (int tj=0; tj<4; tj++) q8[tj] = cat44(qtmp[tj][0], qtmp[tj][1]);
  }
  __syncthreads();

  // ---- s-loop over COMPACTED positions: nsb blocks of 32 ----
  float4v O[4][2], L4[4];
  for (int i=0;i<4;i++){ O[i][0]=zf; O[i][1]=zf; L4[i]=zf; }
  const short one_bf = (short)0x3F80;
  short8 ones8;
  for (int i=0;i<8;i++) ones8[i] = one_bf;

  for (int sb=0; sb<nsb; sb++){
    const int sq = sb*32;
    // C operand: 0 for real positions, -1e30 for pads (16-lane broadcast)
    float4v mm0 = *(const float4v*)(Madd + sq + q4*4);
    float4v mm1 = *(const float4v*)(Madd + sq + 16 + q4*4);
    // K rows for both subtiles (one b128 each, slot swizzle)
    const int srow0 = sq + c, srow1 = sq + 16 + c;
    short8 kb8_0 = *(const short8*)(Kb + srow0*32 + ((q4 ^ (srow0&3))<<3));
    short8 kb8_1 = *(const short8*)(Kb + srow1*32 + ((q4 ^ (srow1&3))<<3));
    // V quads in the SAME compacted-s order as the P fragment's k-slots
    const int u0 = sb*8 + q4, u1 = u0 + 4;
    short4v vA0 = *(const short4v*)(Vt + (size_t)c*T_      + ((u0 + 2*c     ) & 127)*4);
    short4v vA1 = *(const short4v*)(Vt + (size_t)c*T_      + ((u1 + 2*c     ) & 127)*4);
    short4v vB0 = *(const short4v*)(Vt + (size_t)(16+c)*T_ + ((u0 + 32 + 2*c) & 127)*4);
    short4v vB1 = *(const short4v*)(Vt + (size_t)(16+c)*T_ + ((u1 + 32 + 2*c) & 127)*4);
    short8 V8_0 = cat44(vA0, vA1);   // e 0..15
    short8 V8_1 = cat44(vB0, vB1);   // e 16..31
    __builtin_amdgcn_s_setprio(1);
    for (int tj=0; tj<4; tj++){
      float4v st0 = MFMA32(kb8_0, q8[tj], mm0);
      float4v st1 = MFMA32(kb8_1, q8[tj], mm1);
      float4v p0, p1;
      p0[0] = EXP2F(st0[0]); p0[1] = EXP2F(st0[1]);
      p0[2] = EXP2F(st0[2]); p0[3] = EXP2F(st0[3]);
      p1[0] = EXP2F(st1[0]); p1[1] = EXP2F(st1[1]);
      p1[2] = EXP2F(st1[2]); p1[3] = EXP2F(st1[3]);
      short8 A8 = pack8(p0, p1);     // k-slots: [si0 quad | si1 quad]
      O[tj][0] = MFMA32(A8, V8_0, O[tj][0]);
      O[tj][1] = MFMA32(A8, V8_1, O[tj][1]);
      L4[tj]   = MFMA32(A8, ones8, L4[tj]);
    }
    __builtin_amdgcn_s_setprio(0);
  }

  // ---- normalize + direct stores (lane = e, regs = t) ----
  for (int ti=0; ti<4; ti++){
    float4v linv;
    for (int r=0; r<4; r++) linv[r] = __builtin_amdgcn_rcpf(L4[ti][r]);
    for (int ej=0; ej<2; ej++){
      float4v v = O[ti][ej] * linv;
      for (int r=0; r<4; r++){
        int t = t0 + ti*16 + q4*4 + r;
        out[(size_t)((b*T_ + t)*M_ + m)*P_ + h*E_ + ej*16 + c] = v[r];
      }
    }
  }
}

extern "C" void kernel_launch(void* const* d_in, const int* in_sizes, int n_in,
                              void* d_out, int out_size, void* d_ws, size_t ws_size,
                              hipStream_t stream){
  const float* inp = (const float*)d_in[0];
  const int*   msk = (const int*)  d_in[1];
  const float* Wq  = (const float*)d_in[2];
  const float* bq  = (const float*)d_in[3];
  const float* Wk  = (const float*)d_in[4];
  const float* bk  = (const float*)d_in[5];
  const float* Wv  = (const float*)d_in[6];
  const float* bv  = (const float*)d_in[7];
  float* out = (float*)d_out;

  uint16_t* WT = (uint16_t*)d_ws;                          // 196,608 B

  prep<<<dim3(384), dim3(256), 0, stream>>>(Wq, Wk, Wv, WT);
  attn_fused<<<dim3(1024), dim3(512), 0, stream>>>(inp, WT, bq, bk, bv, msk, out);
}

// Round 10
// 153.967 us; speedup vs baseline: 1.0741x; 1.0741x over previous
//
#include <hip/hip_runtime.h>
#include <stdint.h>

#define B_ 8
#define T_ 512
#define M_ 16
#define D_ 128
#define P_ 256
#define H_ 8
#define E_ 32

typedef __attribute__((ext_vector_type(8))) short  short8;
typedef __attribute__((ext_vector_type(4))) short  short4v;
typedef __attribute__((ext_vector_type(4))) float  float4v;
typedef __attribute__((ext_vector_type(2))) unsigned int uint2v;
typedef __attribute__((ext_vector_type(4))) unsigned int uint4v;
typedef __attribute__((ext_vector_type(2))) __bf16 bf16x2;

#define MFMA32(a,b,c) __builtin_amdgcn_mfma_f32_16x16x32_bf16(a,b,c,0,0,0)   // K=32, short8 ops
#define EXP2F(x) __builtin_amdgcn_exp2f(x)

#define C2 0.2550332772062413f   // log2(e)/sqrt(E)

// cold-path scalar RNE (prep only)
static __device__ __forceinline__ unsigned short f2bf(float x){
  unsigned int u = __builtin_bit_cast(unsigned int, x);
  u += 0x7FFFu + ((u >> 16) & 1u);           // RNE
  return (unsigned short)(u >> 16);
}

// hot-path: plain __bf16 casts -> compiler emits v_cvt_pk_bf16_f32 (RNE).
static __device__ __forceinline__ unsigned int pk2(float a, float b){
  bf16x2 h; h[0] = (__bf16)a; h[1] = (__bf16)b;
  return __builtin_bit_cast(unsigned int, h);
}

static __device__ __forceinline__ short4v pack4(float4v v){
  uint2v u; u.x = pk2(v[0], v[1]); u.y = pk2(v[2], v[3]);
  return __builtin_bit_cast(short4v, u);
}

static __device__ __forceinline__ short8 pack8(float4v a, float4v b){
  uint4v u; u.x = pk2(a[0],a[1]); u.y = pk2(a[2],a[3]);
  u.z = pk2(b[0],b[1]); u.w = pk2(b[2],b[3]);
  return __builtin_bit_cast(short8, u);
}

static __device__ __forceinline__ short8 cat44(short4v lo, short4v hi){
  short8 r;
  r[0]=lo[0]; r[1]=lo[1]; r[2]=lo[2]; r[3]=lo[3];
  r[4]=hi[0]; r[5]=hi[1]; r[6]=hi[2]; r[7]=hi[3];
  return r;
}

// ------- kernel 0: WT[z][p][d] bf16 (Wq pre-scaled by C2) --------------------
// Coalesced: p fastest -> contiguous reads. Q/K rows permuted so projection
// passes directly produce the e-chunk-of-8 layout for K=32 MFMA operands:
//   storage row w = eh*16 + q4*4 + r  holds true column  e = q4*8 + eh*4 + r.
__global__ void prep(const float* __restrict__ Wq, const float* __restrict__ Wk,
                     const float* __restrict__ Wv, uint16_t* __restrict__ WT){
  int idx = blockIdx.x*256 + threadIdx.x;      // 384*256 = 98304 = 3*P*D
  int p = idx & (P_-1);
  int d = (idx >> 8) & (D_-1);
  int z = idx >> 15;
  int col = p;
  if (z < 2){                                  // Q, K: permute within-head rows
    int w = p & 31;
    int e = ((w>>2)&3)*8 + ((w>>4)&1)*4 + (w&3);
    col = (p & ~31) | e;
  }
  const float* W = (z==0) ? Wq : (z==1) ? Wk : Wv;
  float sc = (z==0) ? C2 : 1.0f;
  WT[(z<<15) + (p<<7) + d] = f2bf(W[d*P_ + col] * sc);
}

// ---------------- fused QKV + masked attention, one block per (b,m,h) ------
// r10: revert r9's K+V merge (both accumulator sets live simultaneously ->
// +16 regs -> MORE spills, 84MB WRITE; 3rd confirmation: zero reg headroom
// at the 128-reg/4-wave bracket). Back to r8's sequential projections, keep
// r9's tg-via-shfl (-4 persistent regs). New: s-loop SPLIT -- compaction
// means pads exist only in the FINAL s-block, so main iterations use a
// literal zero C operand (no Madd ds_read, QK chain starts at kb read);
// only the tail iteration reads Madd (-1e30 pads).
// r8 recap: mask is block-shared over s, ~50% dense; K/V compacted to
// valid s (ballot+prefix), s-loop runs nsb=ceil(nv/32)~8.5 blocks of 32.
__global__ __launch_bounds__(512, 4) void attn_fused(
    const float* __restrict__ inp, const uint16_t* __restrict__ WT,
    const float* __restrict__ bq, const float* __restrict__ bk,
    const float* __restrict__ bv, const int* __restrict__ mask,
    float* __restrict__ out){
  // bytes [0,65536): staging scratch (512 rows x 128B bf16), later
  //   Kb = [0,32768) K[sc][e] slot-swizzled, Vt = [32768,65536) V^T[e][sc]
  // bytes [65536,67584): Madd (512 f32: 0 for sc<nv, -1e30 pad; tail only)
  // bytes [67584,67616): wcnt (8 ints, per-wave valid counts)
  __shared__ __align__(16) uint16_t smem[(65536 + 2048 + 64)/2];
  uint16_t* Kb   = smem;              // uint16 units: rows of 32 (64B)
  uint16_t* Vt   = smem + 16384;
  float*    Madd = (float*)(smem + 32768);
  int*      wcnt = (int*)(smem + 32768 + 1024);

  const int bx = blockIdx.x;                // 1024
  const int h = bx >> 7, bm = bx & 127;     // same-bm blocks -> same XCD (bx%8 = bm%8)
  const int b = bm >> 4, m = bm & 15;
  const int tid = threadIdx.x;
  const int wave = tid >> 6, lane = tid & 63;
  const int q4 = lane >> 4, c = lane & 15;
  const int t0 = wave*64;

  // own-mask load (s = tid); latency hidden under staging
  const int mv = mask[((size_t)(b*T_ + tid))*M_ + m];

  // ---- stage inp -> LDS (bf16, swizzled) -> read MFMA fragments ----
  // scratch row t: 128B = current 64-d half, 16B slots, slot ^= (t&7)
  short8 af[4][4];   // [tj][kc]
  {
    const float* src0 = inp + (size_t)((b*T_ + t0)*M_ + m)*D_ + c*4;
    for (int hh=0; hh<2; hh++){              // d halves: [0,64), [64,128)
      for (int jb=0; jb<2; jb++){            // 2 batches of 8 loads (reg cap)
        float4v stg[8];
        for (int j=0; j<8; j++){
          int r = jb*32 + j*4 + q4;          // row within wave's 64
          stg[j] = *(const float4v*)(src0 + (size_t)r*(M_*D_) + hh*64);
        }
        for (int j=0; j<8; j++){
          int r = t0 + jb*32 + j*4 + q4;
          short4v s4 = pack4(stg[j]);
          *(short4v*)(smem + r*64 + ((((c>>1) ^ (r&7))<<3) + ((c&1)<<2))) = s4;
        }
      }
      // fragments of this half: kc = hh*2+kh, d = kc*32 + q4*8 .. +7
      for (int tj=0; tj<4; tj++){
        int r2 = t0 + tj*16 + c;
        af[tj][hh*2+0] = *(const short8*)(smem + r2*64 + (((q4    ) ^ (r2&7))<<3));
        af[tj][hh*2+1] = *(const short8*)(smem + r2*64 + (((q4 | 4) ^ (r2&7))<<3));
      }
      // half1 staging overwrites same rows: same-wave DS ops execute in order
    }
  }

  // ---- wave valid-counts (before the barrier) ----
  const unsigned long long bal = __ballot(mv != 0);
  const int lanepfx = __popcll(bal & ((1ull << lane) - 1ull));
  if (lane == 0) wcnt[wave] = __popcll(bal);

  __syncthreads();   // staging scratch free; wcnt visible

  // ---- block prefix: compacted target for s = tid ----
  int off = 0, nv = 0;
  for (int w = 0; w < 8; w++){
    int cw = wcnt[w];
    nv += cw;
    if (w < wave) off += cw;
  }
  nv = __builtin_amdgcn_readfirstlane(nv);
  const int nsb = (nv + 31) >> 5;
  const int myt = (mv != 0) ? (off + lanepfx) : -1;

  // Madd + zero the pad rows of Kb/Vt (disjoint from valid scatter targets)
  Madd[tid] = (tid < nv) ? 0.0f : -1e30f;
  for (int j = nv + tid; j < nsb*32; j += 512){
    short8 z8 = {0,0,0,0,0,0,0,0};
    short8* kp = (short8*)(Kb + j*32);
    kp[0]=z8; kp[1]=z8; kp[2]=z8; kp[3]=z8;
    for (int e = 0; e < E_; e++)
      Vt[e*T_ + ((((j>>2) + 2*e) & 127)*4) + (j&3)] = 0;
  }

  const uint16_t* WQ = WT                       + (size_t)(h*E_)*D_;
  const uint16_t* WK = WT + (size_t)1*P_*D_     + (size_t)(h*E_)*D_;
  const uint16_t* WV = WT + (size_t)2*P_*D_     + (size_t)(h*E_)*D_;
  float4v zf = {0.f,0.f,0.f,0.f};

  // ---- K projection -> Kb[tgt][e]: pass eh yields e = q4*8+eh*4+r ----
  // byte addr = tgt*64 + slot*16 + eh*8, slot = q4 ^ (tgt&3)
  for (int eh=0; eh<2; eh++){
    float4v ka[4]; for (int j=0;j<4;j++) ka[j]=zf;
    for (int kc=0; kc<4; kc++){
      short8 w = *(const short8*)(WK + (size_t)(eh*16 + c)*D_ + kc*32 + q4*8);
      for (int sj=0; sj<4; sj++) ka[sj] = MFMA32(w, af[sj][kc], ka[sj]);
    }
    float4v bk4 = *(const float4v*)(bk + h*E_ + q4*8 + eh*4);
    for (int sj=0; sj<4; sj++){
      int t = __shfl(myt, sj*16 + c);      // compaction target of s=t0+sj*16+c
      short4v kv = pack4(ka[sj] + bk4);
      if (t >= 0)
        *(short4v*)(Kb + t*32 + ((q4 ^ (t&3))<<3) + eh*4) = kv;
    }
  }
  // ---- V projection -> Vt[e][tgt]: slot stagger 2e (conflict-free reads) ----
  for (int eh=0; eh<2; eh++){
    float4v va[4]; for (int j=0;j<4;j++) va[j]=zf;
    for (int kc=0; kc<4; kc++){
      short8 w = *(const short8*)(WV + (size_t)(eh*16 + c)*D_ + kc*32 + q4*8);
      for (int sj=0; sj<4; sj++) va[sj] = MFMA32(w, af[sj][kc], va[sj]);
    }
    float4v bv4 = *(const float4v*)(bv + h*E_ + eh*16 + q4*4);
    for (int sj=0; sj<4; sj++){
      int t = __shfl(myt, sj*16 + c);
      short4v vv = pack4(va[sj] + bv4);
      if (t >= 0){
        for (int r=0; r<4; r++){
          int e = eh*16 + q4*4 + r;
          Vt[e*T_ + ((((t>>2) + 2*e) & 127)*4) + (t&3)] = (uint16_t)vv[r];
        }
      }
    }
  }
  // ---- Q projection -> q8 regs: concat(pass0,pass1) = e chunk q4*8..q4*8+7 ----
  short8 q8[4];
  {
    short4v qtmp[4][2];
    for (int eh=0; eh<2; eh++){
      float4v qa[4]; for (int j=0;j<4;j++) qa[j]=zf;
      for (int kc=0; kc<4; kc++){
        short8 w = *(const short8*)(WQ + (size_t)(eh*16 + c)*D_ + kc*32 + q4*8);
        for (int tj=0; tj<4; tj++) qa[tj] = MFMA32(w, af[tj][kc], qa[tj]);
      }
      float4v bq4 = *(const float4v*)(bq + h*E_ + q4*8 + eh*4);
      bq4 *= C2;
      for (int tj=0; tj<4; tj++) qtmp[tj][eh] = pack4(qa[tj] + bq4);
    }
    for (int tj=0; tj<4; tj++) q8[tj] = cat44(qtmp[tj][0], qtmp[tj][1]);
  }
  __syncthreads();

  // ---- s-loop over COMPACTED positions: nsb blocks of 32 ----
  // sb < nsb-1: no pads -> C operand is literal 0 (no Madd read, shorter
  // QK dependency chain). Tail sb = nsb-1: C from Madd (-1e30 pads).
  float4v O[4][2], L4[4];
  for (int i=0;i<4;i++){ O[i][0]=zf; O[i][1]=zf; L4[i]=zf; }
  const short one_bf = (short)0x3F80;
  short8 ones8;
  for (int i=0;i<8;i++) ones8[i] = one_bf;

#define SBODY(sq_, mm0_, mm1_) do {                                            \
    const int srow0 = (sq_) + c, srow1 = (sq_) + 16 + c;                       \
    short8 kb8_0 = *(const short8*)(Kb + srow0*32 + ((q4 ^ (srow0&3))<<3));    \
    short8 kb8_1 = *(const short8*)(Kb + srow1*32 + ((q4 ^ (srow1&3))<<3));    \
    const int u0 = ((sq_)>>2) + q4, u1 = u0 + 4;                               \
    short4v vA0 = *(const short4v*)(Vt + (size_t)c*T_      + ((u0 + 2*c     ) & 127)*4); \
    short4v vA1 = *(const short4v*)(Vt + (size_t)c*T_      + ((u1 + 2*c     ) & 127)*4); \
    short4v vB0 = *(const short4v*)(Vt + (size_t)(16+c)*T_ + ((u0 + 32 + 2*c) & 127)*4); \
    short4v vB1 = *(const short4v*)(Vt + (size_t)(16+c)*T_ + ((u1 + 32 + 2*c) & 127)*4); \
    short8 V8_0 = cat44(vA0, vA1);   /* e 0..15  */                            \
    short8 V8_1 = cat44(vB0, vB1);   /* e 16..31 */                            \
    __builtin_amdgcn_s_setprio(1);                                             \
    for (int tj=0; tj<4; tj++){                                                \
      float4v st0 = MFMA32(kb8_0, q8[tj], mm0_);                               \
      float4v st1 = MFMA32(kb8_1, q8[tj], mm1_);                               \
      float4v p0, p1;                                                          \
      p0[0] = EXP2F(st0[0]); p0[1] = EXP2F(st0[1]);                            \
      p0[2] = EXP2F(st0[2]); p0[3] = EXP2F(st0[3]);                            \
      p1[0] = EXP2F(st1[0]); p1[1] = EXP2F(st1[1]);                            \
      p1[2] = EXP2F(st1[2]); p1[3] = EXP2F(st1[3]);                            \
      short8 A8 = pack8(p0, p1);     /* k-slots: [si0 quad | si1 quad] */      \
      O[tj][0] = MFMA32(A8, V8_0, O[tj][0]);                                   \
      O[tj][1] = MFMA32(A8, V8_1, O[tj][1]);                                   \
      L4[tj]   = MFMA32(A8, ones8, L4[tj]);                                    \
    }                                                                          \
    __builtin_amdgcn_s_setprio(0);                                             \
  } while(0)

  for (int sb=0; sb<nsb-1; sb++){
    SBODY(sb*32, zf, zf);
  }
  if (nsb > 0){
    const int sq = (nsb-1)*32;
    float4v mm0 = *(const float4v*)(Madd + sq + q4*4);
    float4v mm1 = *(const float4v*)(Madd + sq + 16 + q4*4);
    SBODY(sq, mm0, mm1);
  }
#undef SBODY

  // ---- normalize + direct stores (lane = e, regs = t) ----
  for (int ti=0; ti<4; ti++){
    float4v linv;
    for (int r=0; r<4; r++) linv[r] = __builtin_amdgcn_rcpf(L4[ti][r]);
    for (int ej=0; ej<2; ej++){
      float4v v = O[ti][ej] * linv;
      for (int r=0; r<4; r++){
        int t = t0 + ti*16 + q4*4 + r;
        out[(size_t)((b*T_ + t)*M_ + m)*P_ + h*E_ + ej*16 + c] = v[r];
      }
    }
  }
}

extern "C" void kernel_launch(void* const* d_in, const int* in_sizes, int n_in,
                              void* d_out, int out_size, void* d_ws, size_t ws_size,
                              hipStream_t stream){
  const float* inp = (const float*)d_in[0];
  const int*   msk = (const int*)  d_in[1];
  const float* Wq  = (const float*)d_in[2];
  const float* bq  = (const float*)d_in[3];
  const float* Wk  = (const float*)d_in[4];
  const float* bk  = (const float*)d_in[5];
  const float* Wv  = (const float*)d_in[6];
  const float* bv  = (const float*)d_in[7];
  float* out = (float*)d_out;

  uint16_t* WT = (uint16_t*)d_ws;                          // 196,608 B

  prep<<<dim3(384), dim3(256), 0, stream>>>(Wq, Wk, Wv, WT);
  attn_fused<<<dim3(1024), dim3(512), 0, stream>>>(inp, WT, bq, bk, bv, msk, out);
}

// Round 11
// 151.833 us; speedup vs baseline: 1.0892x; 1.0141x over previous
//
#include <hip/hip_runtime.h>
#include <stdint.h>

#define B_ 8
#define T_ 512
#define M_ 16
#define D_ 128
#define P_ 256
#define H_ 8
#define E_ 32

typedef __attribute__((ext_vector_type(8))) short  short8;
typedef __attribute__((ext_vector_type(4))) short  short4v;
typedef __attribute__((ext_vector_type(4))) float  float4v;
typedef __attribute__((ext_vector_type(2))) unsigned int uint2v;
typedef __attribute__((ext_vector_type(4))) unsigned int uint4v;
typedef __attribute__((ext_vector_type(2))) __bf16 bf16x2;

#define MFMA32(a,b,c) __builtin_amdgcn_mfma_f32_16x16x32_bf16(a,b,c,0,0,0)   // K=32, short8 ops
#define EXP2F(x) __builtin_amdgcn_exp2f(x)

#define C2 0.2550332772062413f   // log2(e)/sqrt(E)

// cold-path scalar RNE (prep only)
static __device__ __forceinline__ unsigned short f2bf(float x){
  unsigned int u = __builtin_bit_cast(unsigned int, x);
  u += 0x7FFFu + ((u >> 16) & 1u);           // RNE
  return (unsigned short)(u >> 16);
}

// hot-path: plain __bf16 casts -> compiler emits v_cvt_pk_bf16_f32 (RNE).
static __device__ __forceinline__ unsigned int pk2(float a, float b){
  bf16x2 h; h[0] = (__bf16)a; h[1] = (__bf16)b;
  return __builtin_bit_cast(unsigned int, h);
}

static __device__ __forceinline__ short4v pack4(float4v v){
  uint2v u; u.x = pk2(v[0], v[1]); u.y = pk2(v[2], v[3]);
  return __builtin_bit_cast(short4v, u);
}

static __device__ __forceinline__ short8 pack8(float4v a, float4v b){
  uint4v u; u.x = pk2(a[0],a[1]); u.y = pk2(a[2],a[3]);
  u.z = pk2(b[0],b[1]); u.w = pk2(b[2],b[3]);
  return __builtin_bit_cast(short8, u);
}

static __device__ __forceinline__ short8 cat44(short4v lo, short4v hi){
  short8 r;
  r[0]=lo[0]; r[1]=lo[1]; r[2]=lo[2]; r[3]=lo[3];
  r[4]=hi[0]; r[5]=hi[1]; r[6]=hi[2]; r[7]=hi[3];
  return r;
}

// ------- kernel 0: WT[z][p][d] bf16 (Wq pre-scaled by C2) --------------------
// Coalesced: p fastest -> contiguous reads. Q/K rows permuted so projection
// passes directly produce the e-chunk-of-8 layout for K=32 MFMA operands:
//   storage row w = eh*16 + q4*4 + r  holds true column  e = q4*8 + eh*4 + r.
__global__ void prep(const float* __restrict__ Wq, const float* __restrict__ Wk,
                     const float* __restrict__ Wv, uint16_t* __restrict__ WT){
  int idx = blockIdx.x*256 + threadIdx.x;      // 384*256 = 98304 = 3*P*D
  int p = idx & (P_-1);
  int d = (idx >> 8) & (D_-1);
  int z = idx >> 15;
  int col = p;
  if (z < 2){                                  // Q, K: permute within-head rows
    int w = p & 31;
    int e = ((w>>2)&3)*8 + ((w>>4)&1)*4 + (w&3);
    col = (p & ~31) | e;
  }
  const float* W = (z==0) ? Wq : (z==1) ? Wk : Wv;
  float sc = (z==0) ? C2 : 1.0f;
  WT[(z<<15) + (p<<7) + d] = f2bf(W[d*P_ + col] * sc);
}

// ---------------- fused QKV + masked attention, one block per (b,m,h) ------
// r11: occupancy is PROVEN double-bound at 16 waves/CU (LDS 66KB->2 blk/CU
// with Kb+Vt=64KB irreducible for worst-case nv=512; regs ~128 incl. unified
// AGPRs -- r3/r6/r9 all spilled when pushed). Final s-loop trim: Vt slot
// order permuted within each aligned 8-group (perm8(j)=((j&3)<<1)|(j>>2))
// so the (u0,u0+4) quad pair is ADJACENT -> one aligned ds_read_b128
// replaces two b64 + cat44, bit-identical operand. 4->2 V reads/iter,
// 2 fewer lgkm slots on the iteration head chain.
// r8-r10 recap: mask block-shared over s, ~50% dense; K/V compacted to
// valid s (ballot+prefix), s-loop nsb=ceil(nv/32)~8.5 blocks; main loop
// uses literal-0 C operand (pads only in the tail block, Madd there).
__global__ __launch_bounds__(512, 4) void attn_fused(
    const float* __restrict__ inp, const uint16_t* __restrict__ WT,
    const float* __restrict__ bq, const float* __restrict__ bk,
    const float* __restrict__ bv, const int* __restrict__ mask,
    float* __restrict__ out){
  // bytes [0,65536): staging scratch (512 rows x 128B bf16), later
  //   Kb = [0,32768) K[sc][e] slot-swizzled, Vt = [32768,65536) V^T[e][sc]
  // bytes [65536,67584): Madd (512 f32: 0 for sc<nv, -1e30 pad; tail only)
  // bytes [67584,67616): wcnt (8 ints, per-wave valid counts)
  __shared__ __align__(16) uint16_t smem[(65536 + 2048 + 64)/2];
  uint16_t* Kb   = smem;              // uint16 units: rows of 32 (64B)
  uint16_t* Vt   = smem + 16384;
  float*    Madd = (float*)(smem + 32768);
  int*      wcnt = (int*)(smem + 32768 + 1024);

  const int bx = blockIdx.x;                // 1024
  const int h = bx >> 7, bm = bx & 127;     // same-bm blocks -> same XCD (bx%8 = bm%8)
  const int b = bm >> 4, m = bm & 15;
  const int tid = threadIdx.x;
  const int wave = tid >> 6, lane = tid & 63;
  const int q4 = lane >> 4, c = lane & 15;
  const int t0 = wave*64;

  // own-mask load (s = tid); latency hidden under staging
  const int mv = mask[((size_t)(b*T_ + tid))*M_ + m];

  // ---- stage inp -> LDS (bf16, swizzled) -> read MFMA fragments ----
  // scratch row t: 128B = current 64-d half, 16B slots, slot ^= (t&7)
  short8 af[4][4];   // [tj][kc]
  {
    const float* src0 = inp + (size_t)((b*T_ + t0)*M_ + m)*D_ + c*4;
    for (int hh=0; hh<2; hh++){              // d halves: [0,64), [64,128)
      for (int jb=0; jb<2; jb++){            // 2 batches of 8 loads (reg cap)
        float4v stg[8];
        for (int j=0; j<8; j++){
          int r = jb*32 + j*4 + q4;          // row within wave's 64
          stg[j] = *(const float4v*)(src0 + (size_t)r*(M_*D_) + hh*64);
        }
        for (int j=0; j<8; j++){
          int r = t0 + jb*32 + j*4 + q4;
          short4v s4 = pack4(stg[j]);
          *(short4v*)(smem + r*64 + ((((c>>1) ^ (r&7))<<3) + ((c&1)<<2))) = s4;
        }
      }
      // fragments of this half: kc = hh*2+kh, d = kc*32 + q4*8 .. +7
      for (int tj=0; tj<4; tj++){
        int r2 = t0 + tj*16 + c;
        af[tj][hh*2+0] = *(const short8*)(smem + r2*64 + (((q4    ) ^ (r2&7))<<3));
        af[tj][hh*2+1] = *(const short8*)(smem + r2*64 + (((q4 | 4) ^ (r2&7))<<3));
      }
      // half1 staging overwrites same rows: same-wave DS ops execute in order
    }
  }

  // ---- wave valid-counts (before the barrier) ----
  const unsigned long long bal = __ballot(mv != 0);
  const int lanepfx = __popcll(bal & ((1ull << lane) - 1ull));
  if (lane == 0) wcnt[wave] = __popcll(bal);

  __syncthreads();   // staging scratch free; wcnt visible

  // ---- block prefix: compacted target for s = tid ----
  int off = 0, nv = 0;
  for (int w = 0; w < 8; w++){
    int cw = wcnt[w];
    nv += cw;
    if (w < wave) off += cw;
  }
  nv = __builtin_amdgcn_readfirstlane(nv);
  const int nsb = (nv + 31) >> 5;
  const int myt = (mv != 0) ? (off + lanepfx) : -1;

  // Madd + zero the pad rows of Kb/Vt (disjoint from valid scatter targets)
  Madd[tid] = (tid < nv) ? 0.0f : -1e30f;
  for (int j = nv + tid; j < nsb*32; j += 512){
    short8 z8 = {0,0,0,0,0,0,0,0};
    short8* kp = (short8*)(Kb + j*32);
    kp[0]=z8; kp[1]=z8; kp[2]=z8; kp[3]=z8;
    int u = j>>2;
    int up = (u & ~7) | ((u&3)<<1) | ((u>>2)&1);   // perm8 within 8-group
    for (int e = 0; e < E_; e++)
      Vt[e*T_ + ((up + 2*e) & 127)*4 + (j&3)] = 0;
  }

  const uint16_t* WQ = WT                       + (size_t)(h*E_)*D_;
  const uint16_t* WK = WT + (size_t)1*P_*D_     + (size_t)(h*E_)*D_;
  const uint16_t* WV = WT + (size_t)2*P_*D_     + (size_t)(h*E_)*D_;
  float4v zf = {0.f,0.f,0.f,0.f};

  // ---- K projection -> Kb[tgt][e]: pass eh yields e = q4*8+eh*4+r ----
  // byte addr = tgt*64 + slot*16 + eh*8, slot = q4 ^ (tgt&3)
  for (int eh=0; eh<2; eh++){
    float4v ka[4]; for (int j=0;j<4;j++) ka[j]=zf;
    for (int kc=0; kc<4; kc++){
      short8 w = *(const short8*)(WK + (size_t)(eh*16 + c)*D_ + kc*32 + q4*8);
      for (int sj=0; sj<4; sj++) ka[sj] = MFMA32(w, af[sj][kc], ka[sj]);
    }
    float4v bk4 = *(const float4v*)(bk + h*E_ + q4*8 + eh*4);
    for (int sj=0; sj<4; sj++){
      int t = __shfl(myt, sj*16 + c);      // compaction target of s=t0+sj*16+c
      short4v kv = pack4(ka[sj] + bk4);
      if (t >= 0)
        *(short4v*)(Kb + t*32 + ((q4 ^ (t&3))<<3) + eh*4) = kv;
    }
  }
  // ---- V projection -> Vt[e][tgt]: perm8 slot order + 2e stagger ----
  // slot(u,e) = ((u&~7)|perm8(u&7)) + 2e  (mod 128); pair (u,u+4) adjacent
  for (int eh=0; eh<2; eh++){
    float4v va[4]; for (int j=0;j<4;j++) va[j]=zf;
    for (int kc=0; kc<4; kc++){
      short8 w = *(const short8*)(WV + (size_t)(eh*16 + c)*D_ + kc*32 + q4*8);
      for (int sj=0; sj<4; sj++) va[sj] = MFMA32(w, af[sj][kc], va[sj]);
    }
    float4v bv4 = *(const float4v*)(bv + h*E_ + eh*16 + q4*4);
    for (int sj=0; sj<4; sj++){
      int t = __shfl(myt, sj*16 + c);
      short4v vv = pack4(va[sj] + bv4);
      if (t >= 0){
        int u = t>>2;
        int up = (u & ~7) | ((u&3)<<1) | ((u>>2)&1);
        for (int r=0; r<4; r++){
          int e = eh*16 + q4*4 + r;
          Vt[e*T_ + ((up + 2*e) & 127)*4 + (t&3)] = (uint16_t)vv[r];
        }
      }
    }
  }
  // ---- Q projection -> q8 regs: concat(pass0,pass1) = e chunk q4*8..q4*8+7 ----
  short8 q8[4];
  {
    short4v qtmp[4][2];
    for (int eh=0; eh<2; eh++){
      float4v qa[4]; for (int j=0;j<4;j++) qa[j]=zf;
      for (int kc=0; kc<4; kc++){
        short8 w = *(const short8*)(WQ + (size_t)(eh*16 + c)*D_ + kc*32 + q4*8);
        for (int tj=0; tj<4; tj++) qa[tj] = MFMA32(w, af[tj][kc], qa[tj]);
      }
      float4v bq4 = *(const float4v*)(bq + h*E_ + q4*8 + eh*4);
      bq4 *= C2;
      for (int tj=0; tj<4; tj++) qtmp[tj][eh] = pack4(qa[tj] + bq4);
    }
    for (int tj=0; tj<4; tj++) q8[tj] = cat44(qtmp[tj][0], qtmp[tj][1]);
  }
  __syncthreads();

  // ---- s-loop over COMPACTED positions: nsb blocks of 32 ----
  // sb < nsb-1: no pads -> C operand is literal 0 (no Madd read, shorter
  // QK dependency chain). Tail sb = nsb-1: C from Madd (-1e30 pads).
  // V: one aligned b128 per e-half -- perm8 layout puts (u0,u0+4) adjacent,
  // base slot (sq>>2) + 2*q4 + 2*e is always even -> 16B-aligned, in-row.
  float4v O[4][2], L4[4];
  for (int i=0;i<4;i++){ O[i][0]=zf; O[i][1]=zf; L4[i]=zf; }
  const short one_bf = (short)0x3F80;
  short8 ones8;
  for (int i=0;i<8;i++) ones8[i] = one_bf;

#define SBODY(sq_, mm0_, mm1_) do {                                            \
    const int srow0 = (sq_) + c, srow1 = (sq_) + 16 + c;                       \
    short8 kb8_0 = *(const short8*)(Kb + srow0*32 + ((q4 ^ (srow0&3))<<3));    \
    short8 kb8_1 = *(const short8*)(Kb + srow1*32 + ((q4 ^ (srow1&3))<<3));    \
    const int vb_ = ((sq_)>>2) + 2*q4 + 2*c;                                   \
    short8 V8_0 = *(const short8*)(Vt + (size_t)c*T_      + ((vb_     ) & 127)*4); \
    short8 V8_1 = *(const short8*)(Vt + (size_t)(16+c)*T_ + ((vb_ + 32) & 127)*4); \
    __builtin_amdgcn_s_setprio(1);                                             \
    for (int tj=0; tj<4; tj++){                                                \
      float4v st0 = MFMA32(kb8_0, q8[tj], mm0_);                               \
      float4v st1 = MFMA32(kb8_1, q8[tj], mm1_);                               \
      float4v p0, p1;                                                          \
      p0[0] = EXP2F(st0[0]); p0[1] = EXP2F(st0[1]);                            \
      p0[2] = EXP2F(st0[2]); p0[3] = EXP2F(st0[3]);                            \
      p1[0] = EXP2F(st1[0]); p1[1] = EXP2F(st1[1]);                            \
      p1[2] = EXP2F(st1[2]); p1[3] = EXP2F(st1[3]);                            \
      short8 A8 = pack8(p0, p1);     /* k-slots: [si0 quad | si1 quad] */      \
      O[tj][0] = MFMA32(A8, V8_0, O[tj][0]);                                   \
      O[tj][1] = MFMA32(A8, V8_1, O[tj][1]);                                   \
      L4[tj]   = MFMA32(A8, ones8, L4[tj]);                                    \
    }                                                                          \
    __builtin_amdgcn_s_setprio(0);                                             \
  } while(0)

  for (int sb=0; sb<nsb-1; sb++){
    SBODY(sb*32, zf, zf);
  }
  if (nsb > 0){
    const int sq = (nsb-1)*32;
    float4v mm0 = *(const float4v*)(Madd + sq + q4*4);
    float4v mm1 = *(const float4v*)(Madd + sq + 16 + q4*4);
    SBODY(sq, mm0, mm1);
  }
#undef SBODY

  // ---- normalize + direct stores (lane = e, regs = t) ----
  for (int ti=0; ti<4; ti++){
    float4v linv;
    for (int r=0; r<4; r++) linv[r] = __builtin_amdgcn_rcpf(L4[ti][r]);
    for (int ej=0; ej<2; ej++){
      float4v v = O[ti][ej] * linv;
      for (int r=0; r<4; r++){
        int t = t0 + ti*16 + q4*4 + r;
        out[(size_t)((b*T_ + t)*M_ + m)*P_ + h*E_ + ej*16 + c] = v[r];
      }
    }
  }
}

extern "C" void kernel_launch(void* const* d_in, const int* in_sizes, int n_in,
                              void* d_out, int out_size, void* d_ws, size_t ws_size,
                              hipStream_t stream){
  const float* inp = (const float*)d_in[0];
  const int*   msk = (const int*)  d_in[1];
  const float* Wq  = (const float*)d_in[2];
  const float* bq  = (const float*)d_in[3];
  const float* Wk  = (const float*)d_in[4];
  const float* bk  = (const float*)d_in[5];
  const float* Wv  = (const float*)d_in[6];
  const float* bv  = (const float*)d_in[7];
  float* out = (float*)d_out;

  uint16_t* WT = (uint16_t*)d_ws;                          // 196,608 B

  prep<<<dim3(384), dim3(256), 0, stream>>>(Wq, Wk, Wv, WT);
  attn_fused<<<dim3(1024), dim3(512), 0, stream>>>(inp, WT, bq, bk, bv, msk, out);
}